// Round 3
// baseline (1008.378 us; speedup 1.0000x reference)
//
#include <hip/hip_runtime.h>
#include <hip/hip_bf16.h>

#define NN 20000
#define NP 20032            // padded to 32*626
#define NE 320000
#define RR 8
#define DD 256
#define LL 6
#define EED 32
#define BB 64
#define KK 32
#define MM (NN * RR)        // 160000 segments, key = dst*8 + rel
#define NSB 79              // scan blocks: ceil(160000 / 2048)
#define NB2 626             // row blocks of 32
#define HSTR 260            // padded h-tile row stride (floats)
#define ES_CAP 1280         // per-block staged edge-list capacity (avg 512, max ~650)

typedef __bf16 bf8 __attribute__((ext_vector_type(8)));
typedef float f4 __attribute__((ext_vector_type(4)));

__device__ inline float lo2f(unsigned v) { return __uint_as_float(v << 16); }
__device__ inline float hi2f(unsigned v) { return __uint_as_float(v & 0xffff0000u); }
__device__ inline unsigned short f2bf(float f) {
    unsigned u = __float_as_uint(f);
    return (unsigned short)((u + 0x7fff + ((u >> 16) & 1)) >> 16);
}
__device__ inline unsigned pack2(float lo, float hi) {
    return (unsigned)f2bf(lo) | ((unsigned)f2bf(hi) << 16);
}

// ---------------- CSR build (once per call) ----------------

__global__ __launch_bounds__(256) void hist_kernel(const int* __restrict__ dstv,
                                                   const int* __restrict__ typev,
                                                   int* __restrict__ hist) {
    int e = blockIdx.x * 256 + threadIdx.x;
    if (e < NE) atomicAdd(&hist[dstv[e] * 8 + typev[e]], 1);
}

__global__ __launch_bounds__(256) void scan1_kernel(const int* __restrict__ hist,
                                                    int* __restrict__ excl,
                                                    int* __restrict__ bsums) {
    __shared__ int tmp[256];
    int tid = threadIdx.x;
    int base = blockIdx.x * 2048 + tid * 8;
    int v[8]; int s = 0;
#pragma unroll
    for (int i = 0; i < 8; ++i) {
        v[i] = (base + i < MM) ? hist[base + i] : 0;
        s += v[i];
    }
    tmp[tid] = s;
    __syncthreads();
    for (int off = 1; off < 256; off <<= 1) {
        int t = (tid >= off) ? tmp[tid - off] : 0;
        __syncthreads();
        tmp[tid] += t;
        __syncthreads();
    }
    int run = tmp[tid] - s;
#pragma unroll
    for (int i = 0; i < 8; ++i) {
        if (base + i < MM) excl[base + i] = run;
        run += v[i];
    }
    if (tid == 255) bsums[blockIdx.x] = tmp[255];
}

__global__ __launch_bounds__(128) void scan2_kernel(int* __restrict__ bsums) {
    __shared__ int tmp[128];
    int tid = threadIdx.x;
    int orig = (tid < NSB) ? bsums[tid] : 0;
    tmp[tid] = orig;
    __syncthreads();
    for (int off = 1; off < 128; off <<= 1) {
        int t = (tid >= off) ? tmp[tid - off] : 0;
        __syncthreads();
        tmp[tid] += t;
        __syncthreads();
    }
    if (tid < NSB) bsums[tid] = tmp[tid] - orig;
}

__global__ __launch_bounds__(256) void add_off_kernel(const int* __restrict__ excl,
                                                      const int* __restrict__ bsums,
                                                      int* __restrict__ seg_start,
                                                      int* __restrict__ cursor) {
    int i = blockIdx.x * 256 + threadIdx.x;
    if (i < MM) {
        int v = excl[i] + bsums[i >> 11];
        seg_start[i] = v;
        cursor[i] = v;
    }
    if (i == 0) seg_start[MM] = NE;
}

__global__ __launch_bounds__(256) void sort_scatter_kernel(
    const int* __restrict__ srcv, const int* __restrict__ dstv,
    const int* __restrict__ typev, int* __restrict__ cursor,
    int* __restrict__ esrc, int* __restrict__ eid) {
    int e = blockIdx.x * 256 + threadIdx.x;
    if (e < NE) {
        int key = dstv[e] * 8 + typev[e];
        int pos = atomicAdd(&cursor[key], 1);
        esrc[pos] = srcv[e];
        eid[pos]  = e;
    }
}

__global__ __launch_bounds__(256) void invdeg_kernel(const int* __restrict__ seg_start,
                                                     float* __restrict__ invdeg) {
    int i = blockIdx.x * 256 + threadIdx.x;
    if (i < NN) {
        int d = seg_start[i * 8 + 8] - seg_start[i * 8];
        invdeg[i] = 1.0f / (float)max(d, 1);
    }
}

// ---------------- once-per-call precomputes ----------------

__global__ __launch_bounds__(256) void eagg_kernel(
    const int* __restrict__ seg_start, const int* __restrict__ eid,
    const float* __restrict__ ee, const float* __restrict__ invdeg,
    unsigned short* __restrict__ eaggbf) {
    int tid = threadIdx.x;
    int s = blockIdx.x * 8 + (tid >> 5);
    int j = tid & 31;
    int n = s >> 3, r = s & 7;
    int j0 = seg_start[s], j1 = seg_start[s + 1];
    float sum = 0.0f;
    for (int p = j0; p < j1; ++p)
        sum += ee[eid[p] * EED + j];
    eaggbf[(size_t)n * DD + r * EED + j] = f2bf(sum * invdeg[n]);
}

// Whe split-K over 8 d-chunks of 32, fp32 atomics (Whe pre-zeroed)
__global__ __launch_bounds__(256) void whe_kernel(const float* __restrict__ We,
                                                  const float* __restrict__ W,
                                                  float* __restrict__ Whe) {
    __shared__ float WeS[EED * 32];
    int b = blockIdx.x;
    int l = b >> 6;
    int r = (b >> 3) & 7;
    int dc = b & 7;
    int tid = threadIdx.x;
    {
        int j = tid >> 3, dl = (tid & 7) * 4;
        *(float4*)&WeS[j * 32 + dl] =
            *(const float4*)&We[(size_t)l * EED * DD + (size_t)j * DD + dc * 32 + dl];
    }
    __syncthreads();
    const float* Wr = W + ((size_t)l * 8 + r) * DD * DD + (size_t)dc * 32 * DD;
    float acc[EED];
#pragma unroll
    for (int j = 0; j < EED; ++j) acc[j] = 0.0f;
    for (int dl = 0; dl < 32; ++dl) {
        float w = Wr[(size_t)dl * DD + tid];
#pragma unroll
        for (int j = 0; j < EED; ++j) acc[j] += WeS[j * 32 + dl] * w;
    }
    float* outp = Whe + (size_t)l * DD * DD + r * EED * DD + tid;
#pragma unroll
    for (int j = 0; j < EED; ++j) unsafeAtomicAdd(&outp[j * DD], acc[j]);
}

// B pre-swizzle into MFMA fragment order (bf16).
// Phase order: p=0 -> Wself, p=1..8 -> W[r=p-1], p=9 -> Whe.
// Bsw[l][(((p*8+kb)*4+quad)*256+f)*8+j] = B_l[p][kb*32+quad*8+j][f]
__global__ __launch_bounds__(256) void bswz_kernel(const float* __restrict__ W,
                                                   const float* __restrict__ Wself,
                                                   const float* __restrict__ Whe,
                                                   unsigned short* __restrict__ Bsw) {
    int gid = blockIdx.x * 256 + threadIdx.x;
    int f = gid & 255;
    int t = gid >> 8;
    int quad = t & 3; t >>= 2;
    int kb = t & 7; t >>= 3;
    int p = t % 10, l = t / 10;
    const float* base = (p == 0) ? Wself + (size_t)l * DD * DD
                      : (p <= 8) ? W + ((size_t)l * 8 + (p - 1)) * DD * DD
                                 : Whe + (size_t)l * DD * DD;
    int k0 = kb * 32 + quad * 8;
    unsigned pk[4];
#pragma unroll
    for (int jj = 0; jj < 4; ++jj)
        pk[jj] = pack2(base[(size_t)(k0 + 2 * jj) * DD + f],
                       base[(size_t)(k0 + 2 * jj + 1) * DD + f]);
    uint4 v = make_uint4(pk[0], pk[1], pk[2], pk[3]);
    *(uint4*)&Bsw[(size_t)gid * 8] = v;
}

__global__ __launch_bounds__(256) void init_x_kernel(float* __restrict__ x,
                                                     unsigned short* __restrict__ xbf) {
    int i = blockIdx.x * 256 + threadIdx.x;
    ((float4*)x)[i] = make_float4(1.f, 1.f, 1.f, 1.f);
    ((uint2*)xbf)[i] = make_uint2(0x3f803f80u, 0x3f803f80u);
}

// ------- fused per-layer kernel: homogeneous waves, gather + MFMA + LN -------
// Block = 32 dst rows x 256 cols, 8 waves (512 thr), HOMOGENEOUS:
//   every wave GATHERS its 4 rows (rows wv*4..+3) for relation p into the
//   next buffer, then runs the MFMA for its 32-col slice (cols wv*32..+31)
//   on the current buffer. Cross-phase pipeline: gather loads for relation p
//   are issued during phase p-1, so they get a full phase of latency budget.
// Round-2 lessons baked in:
//   1. Phase loop is ROLLED (#pragma unroll 1): the unrolled 10-phase body was
//      ~50KB, thrashing the 32KB L1I -> all pipes idle. Body now ~4KB.
//   2. Barrier asm has NO "memory" clobber: a memory-clobber asm makes the
//      waitcnt pass drain vmcnt(0) every phase, killing the pipeline (this is
//      why rounds 0 and 2 measured identical). m201 pattern: sched_barrier(0);
//      s_waitcnt lgkmcnt(0); s_barrier; sched_barrier(0).
//   3. Homogeneous waves halve per-wave state (gv[4][4]=32, breg[2][2]=16,
//      acc[2][2]=16) -> target <=128 total regs for 2 blocks/CU, and double
//      MFMA issue width (8 waves x 32 cols vs 4 x 64).
// Phases: p=0 self/x (buf0 from prologue), p=1..8 relation r=p-1, p=9 eagg/Whe.
// eagg loads issued at p=7 into freed gv slots, staged into buf1 at p=8.
// LDS: 2x16KB buffers + 1040B bounds + ES_CAP*4 edge srcs = 38928B.
__global__ __launch_bounds__(512, 2) void fused_layer_kernel(
    const int* __restrict__ seg_start, const int* __restrict__ esrc,
    const unsigned short* __restrict__ xbf, const unsigned short* __restrict__ eaggbf,
    const unsigned short* __restrict__ Bswl, const float* __restrict__ xin,
    const float* __restrict__ gl, const float* __restrict__ bl,
    float* __restrict__ xout, unsigned short* __restrict__ xbfout) {
    __shared__ __align__(16) unsigned char smem[32768 + 1040 + ES_CAP * 4];
    float* Hs = (float*)smem;                       // epilogue overlay (32 x HSTR)
    int* boundsS = (int*)(smem + 32768);            // 257 seg bounds
    int* esrcS   = (int*)(smem + 32768 + 1040);     // staged edge srcs
    int tid = threadIdx.x;
    int wv = tid >> 6, lane = tid & 63;
    int row0 = blockIdx.x * 32;
    int m = lane & 15, quad = lane >> 4;
    int colg = lane >> 1, half = lane & 1, cofs = lane * 4;
    f4 acc[2][2] = {};

    // ---- prologue: bounds, x tile, edge list, B prefetch, rel-0 gather issue ----
    if (tid < 257) {
        int idx = row0 * 8 + tid;
        boundsS[tid] = (idx <= MM) ? seg_start[idx] : NE;   // pad rows -> empty
    }
    uint4 xs[2];
#pragma unroll
    for (int c = 0; c < 2; ++c) {
        int i = tid + c * 512;
        int row = i >> 5, sc = i & 31;
        xs[c] = *(const uint4*)&xbf[(size_t)(row0 + row) * DD + sc * 8];
    }
    __syncthreads();                                // bounds visible
    int blk0 = boundsS[0];
    int blkE = boundsS[256] - blk0;
    for (int j = tid; j < ES_CAP; j += 512)
        esrcS[j] = (j < blkE) ? esrc[blk0 + j] : 0; // always-valid node ids
#pragma unroll
    for (int c = 0; c < 2; ++c) {
        int i = tid + c * 512;
        int row = i >> 5, sc = i & 31;
        *(uint4*)&smem[row * 512 + ((sc ^ row) * 16)] = xs[c];     // x -> buf0
    }
    int jroll[4];
    float idgr[4];
#pragma unroll
    for (int i4 = 0; i4 < 4; ++i4) {
        int nl = wv * 4 + i4;
        jroll[i4] = boundsS[nl * 8] - blk0;         // j0 of relation 0
        int dg = boundsS[nl * 8 + 8] - boundsS[nl * 8];
        idgr[i4] = 1.0f / (float)max(dg, 1);
    }
    bf8 breg[2][2];
#pragma unroll
    for (int nt = 0; nt < 2; ++nt) {
        breg[0][nt] = *(const bf8*)&Bswl[((size_t)quad * 256 + wv * 32 + nt * 16 + m) * 8];
        breg[1][nt] = *(const bf8*)&Bswl[((size_t)(4 + quad) * 256 + wv * 32 + nt * 16 + m) * 8];
    }
    __syncthreads();                                // esrcS + buf0 visible

    // issue relation-0 gather batch (consumed at phase p=0)
    uint2 gv[4][4];
#pragma unroll
    for (int i4 = 0; i4 < 4; ++i4)
#pragma unroll
        for (int s = 0; s < 4; ++s) {
            int jc = jroll[i4] + s;
            jc = (jc < ES_CAP) ? jc : (ES_CAP - 1);
            gv[i4][s] = *(const uint2*)&xbf[(size_t)esrcS[jc] * DD + cofs];
        }

#pragma unroll 1
    for (int p = 0; p < 10; ++p) {
        unsigned char* bufp = smem + (p & 1) * 16384;
        unsigned char* bufn = smem + ((p + 1) & 1) * 16384;
        if (p < 8) {
            // ---- gather: finish relation p for my 4 rows -> bufn; re-issue next ----
#pragma unroll
            for (int i4 = 0; i4 < 4; ++i4) {
                int nl = wv * 4 + i4;
                int j0 = jroll[i4];
                int j1 = boundsS[nl * 8 + p + 1] - blk0;
                float a0 = 0.f, a1 = 0.f, a2 = 0.f, a3 = 0.f;
#pragma unroll
                for (int s = 0; s < 4; ++s) {
                    unsigned vx = (j0 + s < j1) ? gv[i4][s].x : 0u;
                    unsigned vy = (j0 + s < j1) ? gv[i4][s].y : 0u;
                    a0 += lo2f(vx); a1 += hi2f(vx);
                    a2 += lo2f(vy); a3 += hi2f(vy);
                }
                if (p < 7) {                          // issue next-relation batch
#pragma unroll
                    for (int s = 0; s < 4; ++s) {
                        int jc = j1 + s;
                        jc = (jc < ES_CAP) ? jc : (ES_CAP - 1);
                        gv[i4][s] = *(const uint2*)&xbf[(size_t)esrcS[jc] * DD + cofs];
                    }
                } else {                              // p==7: issue eagg row load
                    gv[i4][0] = *(const uint2*)&eaggbf[(size_t)(row0 + nl) * DD + cofs];
                }
                for (int j = j0 + 4; j < j1; ++j) {   // rare tail (>4 edges/seg)
                    int src = (j < ES_CAP) ? esrcS[j] : esrc[blk0 + j];
                    uint2 v = *(const uint2*)&xbf[(size_t)src * DD + cofs];
                    a0 += lo2f(v.x); a1 += hi2f(v.x);
                    a2 += lo2f(v.y); a3 += hi2f(v.y);
                }
                float idg = idgr[i4];
                *(uint2*)&bufn[nl * 512 + ((colg ^ nl) * 16) + half * 8] =
                    make_uint2(pack2(a0 * idg, a1 * idg), pack2(a2 * idg, a3 * idg));
                jroll[i4] = j1;
            }
        } else if (p == 8) {
            // ---- stage eagg rows (loaded at p=7) into bufn for phase 9 ----
#pragma unroll
            for (int i4 = 0; i4 < 4; ++i4) {
                int nl = wv * 4 + i4;
                *(uint2*)&bufn[nl * 512 + ((colg ^ nl) * 16) + half * 8] = gv[i4][0];
            }
        }
        // ---- 8 MFMA steps on bufp; B register-prefetch 2 steps ahead ----
#pragma unroll
        for (int kb = 0; kb < 8; ++kb) {
            bf8 afr[2];
#pragma unroll
            for (int mt = 0; mt < 2; ++mt) {
                int rowl = mt * 16 + m;
                afr[mt] = *(bf8*)&bufp[rowl * 512 + (((kb * 4 + quad) ^ rowl) * 16)];
            }
#pragma unroll
            for (int mt = 0; mt < 2; ++mt)
#pragma unroll
                for (int nt = 0; nt < 2; ++nt)
                    acc[mt][nt] = __builtin_amdgcn_mfma_f32_16x16x32_bf16(
                        afr[mt], breg[kb & 1][nt], acc[mt][nt], 0, 0, 0);
            int gn = p * 8 + kb + 2;
            if (gn < 80) {
#pragma unroll
                for (int nt = 0; nt < 2; ++nt)
                    breg[kb & 1][nt] = *(const bf8*)&Bswl[((size_t)gn * 4 + quad) * 2048
                                                          + ((size_t)(wv * 32 + nt * 16 + m)) * 8];
            }
        }
        // raw phase barrier: drain LDS ops only; VMEM (gathers + B prefetch)
        // stays in flight. NO memory clobber (it would force a vmcnt(0) drain).
        __builtin_amdgcn_sched_barrier(0);
        asm volatile("s_waitcnt lgkmcnt(0)");
        __builtin_amdgcn_s_barrier();
        __builtin_amdgcn_sched_barrier(0);
    }

    // ---- epilogue: residual prefetch; h tile through LDS; LN+ReLU+residual ----
    float4 xvr[4];
#pragma unroll
    for (int rr = 0; rr < 4; ++rr) {
        int row = wv * 4 + rr;
        xvr[rr] = *(const float4*)&xin[(size_t)(row0 + row) * DD + lane * 4];
    }
    float4 g  = *(const float4*)&gl[lane * 4];
    float4 bb = *(const float4*)&bl[lane * 4];
#pragma unroll
    for (int mt = 0; mt < 2; ++mt)
#pragma unroll
        for (int nt = 0; nt < 2; ++nt)
#pragma unroll
            for (int rg = 0; rg < 4; ++rg)
                Hs[(mt * 16 + quad * 4 + rg) * HSTR + wv * 32 + nt * 16 + m] = acc[mt][nt][rg];
    __syncthreads();
#pragma unroll
    for (int rr = 0; rr < 4; ++rr) {
        int row = wv * 4 + rr;
        float4 v = *(float4*)&Hs[row * HSTR + lane * 4];
        float s = v.x + v.y + v.z + v.w;
        float q = v.x * v.x + v.y * v.y + v.z * v.z + v.w * v.w;
#pragma unroll
        for (int off = 32; off; off >>= 1) {
            s += __shfl_xor(s, off);
            q += __shfl_xor(q, off);
        }
        float mu  = s * (1.0f / DD);
        float var = q * (1.0f / DD) - mu * mu;
        float rs  = rsqrtf(var + 1e-5f);
        size_t xi = (size_t)(row0 + row) * DD + lane * 4;
        float4 xv = xvr[rr];
        float4 o;
        o.x = fmaxf((v.x - mu) * rs * g.x + bb.x, 0.0f) + xv.x;
        o.y = fmaxf((v.y - mu) * rs * g.y + bb.y, 0.0f) + xv.y;
        o.z = fmaxf((v.z - mu) * rs * g.z + bb.z, 0.0f) + xv.z;
        o.w = fmaxf((v.w - mu) * rs * g.w + bb.w, 0.0f) + xv.w;
        *(float4*)&xout[xi] = o;
        *(uint2*)&xbfout[xi] = make_uint2(pack2(o.x, o.y), pack2(o.z, o.w));
    }
}

__global__ __launch_bounds__(256) void score_kernel(
    const int* __restrict__ batch, const float* __restrict__ x,
    const float* __restrict__ rel_emb, float* __restrict__ out) {
    int tid = threadIdx.x;
    int wave = tid >> 6, lane = tid & 63;
    int idx = blockIdx.x * 4 + wave;
    int s = batch[idx * 3 + 0], t = batch[idx * 3 + 1], r = batch[idx * 3 + 2];
    float4 sv = *(const float4*)&x[(size_t)s * DD + lane * 4];
    float4 tv = *(const float4*)&x[(size_t)t * DD + lane * 4];
    float4 rv = *(const float4*)&rel_emb[(size_t)r * DD + lane * 4];
    float sum = sv.x * rv.x * tv.x + sv.y * rv.y * tv.y +
                sv.z * rv.z * tv.z + sv.w * rv.w * tv.w;
#pragma unroll
    for (int off = 32; off; off >>= 1) sum += __shfl_xor(sum, off);
    if (lane == 0) out[idx] = sum;
}

extern "C" void kernel_launch(void* const* d_in, const int* in_sizes, int n_in,
                              void* d_out, int out_size, void* d_ws, size_t ws_size,
                              hipStream_t stream) {
    const int*   edge_index = (const int*)d_in[0];
    const int*   srcv   = edge_index;
    const int*   dstv   = edge_index + NE;
    const int*   typev  = (const int*)d_in[1];
    const float* ee     = (const float*)d_in[2];
    const int*   batch  = (const int*)d_in[3];
    const float* W      = (const float*)d_in[4];
    const float* Wself  = (const float*)d_in[5];
    const float* We     = (const float*)d_in[6];
    const float* gamma  = (const float*)d_in[7];
    const float* beta   = (const float*)d_in[8];
    const float* rel_emb= (const float*)d_in[9];
    float* out = (float*)d_out;

    // workspace layout
    float* xA     = (float*)d_ws;                          // NP*256 f32
    float* xB     = xA + (size_t)NP * DD;                  // NP*256 f32
    float* Whe    = xB + (size_t)NP * DD;                  // L*256*256 f32
    float* invdeg = Whe + (size_t)LL * DD * DD;            // NN f32
    unsigned short* xbfA   = (unsigned short*)(invdeg + NN);          // NP*256
    unsigned short* xbfB   = xbfA + (size_t)NP * DD;                  // NP*256
    unsigned short* eaggbf = xbfB + (size_t)NP * DD;                  // NP*256
    unsigned short* Bsw    = eaggbf + (size_t)NP * DD;                // L*2560*256
    int* hist      = (int*)(Bsw + (size_t)LL * 2560 * DD);            // M
    int* excl      = hist + MM;
    int* seg_start = excl + MM;                                       // M+1
    int* cursor    = seg_start + MM + 1;
    int* bsums     = cursor + MM;                                     // 256
    int* esrc      = bsums + 256;                                     // E
    int* eid       = esrc + NE;                                       // E

    // ---- CSR build ----
    hipMemsetAsync(hist, 0, MM * sizeof(int), stream);
    hist_kernel<<<(NE + 255) / 256, 256, 0, stream>>>(dstv, typev, hist);
    scan1_kernel<<<NSB, 256, 0, stream>>>(hist, excl, bsums);
    scan2_kernel<<<1, 128, 0, stream>>>(bsums);
    add_off_kernel<<<(MM + 255) / 256, 256, 0, stream>>>(excl, bsums, seg_start, cursor);
    invdeg_kernel<<<(NN + 255) / 256, 256, 0, stream>>>(seg_start, invdeg);
    sort_scatter_kernel<<<(NE + 255) / 256, 256, 0, stream>>>(srcv, dstv, typev, cursor, esrc, eid);

    // ---- precomputes ----
    eagg_kernel<<<MM / 8, 256, 0, stream>>>(seg_start, eid, ee, invdeg, eaggbf);
    hipMemsetAsync(Whe, 0, (size_t)LL * DD * DD * sizeof(float), stream);
    whe_kernel<<<LL * 64, 256, 0, stream>>>(We, W, Whe);
    bswz_kernel<<<LL * 10 * 8 * 4, 256, 0, stream>>>(W, Wself, Whe, Bsw);
    init_x_kernel<<<(NP * DD / 4) / 256, 256, 0, stream>>>(xA, xbfA);

    // ---- layers (x double-buffered), homogeneous fused kernel ----
    float* xin = xA;  float* xout = xB;
    unsigned short* xbin = xbfA;  unsigned short* xbout = xbfB;
    for (int l = 0; l < LL; ++l) {
        fused_layer_kernel<<<NB2, 512, 0, stream>>>(seg_start, esrc, xbin, eaggbf,
            Bsw + (size_t)l * 2560 * DD, xin,
            gamma + (size_t)l * DD, beta + (size_t)l * DD, xout, xbout);
        float* t = xin; xin = xout; xout = t;
        unsigned short* tb = xbin; xbin = xbout; xbout = tb;
    }
    score_kernel<<<(BB * KK) / 4, 256, 0, stream>>>(batch, xin, rel_emb, out);
}

// Round 4
// 828.727 us; speedup vs baseline: 1.2168x; 1.2168x over previous
//
#include <hip/hip_runtime.h>
#include <hip/hip_bf16.h>

#define NN 20000
#define NP 20080            // padded to 80*251 (k2 tile) — also covers 32/8 granularity
#define NE 320000
#define RR 8
#define DD 256
#define LL 6
#define EED 32
#define BB 64
#define KK 32
#define MM (NN * RR)        // 160000 segments, key = dst*8 + rel
#define NSB 79              // scan blocks: ceil(160000 / 2048)
#define BMR 80              // k2 row-tile
#define NGB 251             // k2 grid = NP / BMR  (<= 256 CUs -> single round)

typedef __bf16 bf8 __attribute__((ext_vector_type(8)));
typedef float f4 __attribute__((ext_vector_type(4)));

__device__ inline float lo2f(unsigned v) { return __uint_as_float(v << 16); }
__device__ inline float hi2f(unsigned v) { return __uint_as_float(v & 0xffff0000u); }
__device__ inline unsigned short f2bf(float f) {
    unsigned u = __float_as_uint(f);
    return (unsigned short)((u + 0x7fff + ((u >> 16) & 1)) >> 16);
}
__device__ inline unsigned pack2(float lo, float hi) {
    return (unsigned)f2bf(lo) | ((unsigned)f2bf(hi) << 16);
}

// global->LDS direct copy, 16B per lane. LDS dest is linear (wave base + lane*16);
// swizzling lives in the per-lane GLOBAL source address (m173 pattern).
#define GLOAD_LDS16(src, dst)                                                  \
    __builtin_amdgcn_global_load_lds(                                          \
        (const __attribute__((address_space(1))) unsigned int*)(src),          \
        (__attribute__((address_space(3))) unsigned int*)(dst), 16, 0, 0)

// ---------------- CSR build (once per call) ----------------

__global__ __launch_bounds__(256) void hist_kernel(const int* __restrict__ dstv,
                                                   const int* __restrict__ typev,
                                                   int* __restrict__ hist) {
    int e = blockIdx.x * 256 + threadIdx.x;
    if (e < NE) atomicAdd(&hist[dstv[e] * 8 + typev[e]], 1);
}

__global__ __launch_bounds__(256) void scan1_kernel(const int* __restrict__ hist,
                                                    int* __restrict__ excl,
                                                    int* __restrict__ bsums) {
    __shared__ int tmp[256];
    int tid = threadIdx.x;
    int base = blockIdx.x * 2048 + tid * 8;
    int v[8]; int s = 0;
#pragma unroll
    for (int i = 0; i < 8; ++i) {
        v[i] = (base + i < MM) ? hist[base + i] : 0;
        s += v[i];
    }
    tmp[tid] = s;
    __syncthreads();
    for (int off = 1; off < 256; off <<= 1) {
        int t = (tid >= off) ? tmp[tid - off] : 0;
        __syncthreads();
        tmp[tid] += t;
        __syncthreads();
    }
    int run = tmp[tid] - s;
#pragma unroll
    for (int i = 0; i < 8; ++i) {
        if (base + i < MM) excl[base + i] = run;
        run += v[i];
    }
    if (tid == 255) bsums[blockIdx.x] = tmp[255];
}

__global__ __launch_bounds__(128) void scan2_kernel(int* __restrict__ bsums) {
    __shared__ int tmp[128];
    int tid = threadIdx.x;
    int orig = (tid < NSB) ? bsums[tid] : 0;
    tmp[tid] = orig;
    __syncthreads();
    for (int off = 1; off < 128; off <<= 1) {
        int t = (tid >= off) ? tmp[tid - off] : 0;
        __syncthreads();
        tmp[tid] += t;
        __syncthreads();
    }
    if (tid < NSB) bsums[tid] = tmp[tid] - orig;
}

__global__ __launch_bounds__(256) void add_off_kernel(const int* __restrict__ excl,
                                                      const int* __restrict__ bsums,
                                                      int* __restrict__ seg_start,
                                                      int* __restrict__ cursor) {
    int i = blockIdx.x * 256 + threadIdx.x;
    if (i < MM) {
        int v = excl[i] + bsums[i >> 11];
        seg_start[i] = v;
        cursor[i] = v;
    }
    if (i == 0) seg_start[MM] = NE;
}

__global__ __launch_bounds__(256) void sort_scatter_kernel(
    const int* __restrict__ srcv, const int* __restrict__ dstv,
    const int* __restrict__ typev, int* __restrict__ cursor,
    int* __restrict__ esrc, int* __restrict__ eid) {
    int e = blockIdx.x * 256 + threadIdx.x;
    if (e < NE) {
        int key = dstv[e] * 8 + typev[e];
        int pos = atomicAdd(&cursor[key], 1);
        esrc[pos] = srcv[e];
        eid[pos]  = e;
    }
}

__global__ __launch_bounds__(256) void invdeg_kernel(const int* __restrict__ seg_start,
                                                     float* __restrict__ invdeg) {
    int i = blockIdx.x * 256 + threadIdx.x;
    if (i < NN) {
        int d = seg_start[i * 8 + 8] - seg_start[i * 8];
        invdeg[i] = 1.0f / (float)max(d, 1);
    }
}

// ---------------- once-per-call precomputes ----------------

__global__ __launch_bounds__(256) void eagg_kernel(
    const int* __restrict__ seg_start, const int* __restrict__ eid,
    const float* __restrict__ ee, const float* __restrict__ invdeg,
    unsigned short* __restrict__ eaggbf) {
    int tid = threadIdx.x;
    int s = blockIdx.x * 8 + (tid >> 5);
    int j = tid & 31;
    int n = s >> 3, r = s & 7;
    int j0 = seg_start[s], j1 = seg_start[s + 1];
    float sum = 0.0f;
    for (int p = j0; p < j1; ++p)
        sum += ee[eid[p] * EED + j];
    eaggbf[(size_t)n * DD + r * EED + j] = f2bf(sum * invdeg[n]);
}

// Whe split-K over 8 d-chunks of 32, fp32 atomics (Whe pre-zeroed)
__global__ __launch_bounds__(256) void whe_kernel(const float* __restrict__ We,
                                                  const float* __restrict__ W,
                                                  float* __restrict__ Whe) {
    __shared__ float WeS[EED * 32];
    int b = blockIdx.x;
    int l = b >> 6;
    int r = (b >> 3) & 7;
    int dc = b & 7;
    int tid = threadIdx.x;
    {
        int j = tid >> 3, dl = (tid & 7) * 4;
        *(float4*)&WeS[j * 32 + dl] =
            *(const float4*)&We[(size_t)l * EED * DD + (size_t)j * DD + dc * 32 + dl];
    }
    __syncthreads();
    const float* Wr = W + ((size_t)l * 8 + r) * DD * DD + (size_t)dc * 32 * DD;
    float acc[EED];
#pragma unroll
    for (int j = 0; j < EED; ++j) acc[j] = 0.0f;
    for (int dl = 0; dl < 32; ++dl) {
        float w = Wr[(size_t)dl * DD + tid];
#pragma unroll
        for (int j = 0; j < EED; ++j) acc[j] += WeS[j * 32 + dl] * w;
    }
    float* outp = Whe + (size_t)l * DD * DD + r * EED * DD + tid;
#pragma unroll
    for (int j = 0; j < EED; ++j) unsafeAtomicAdd(&outp[j * DD], acc[j]);
}

// B pre-swizzle into MFMA fragment order (bf16).
// Phase order: p=0 -> Wself, p=1..8 -> W[r=p-1], p=9 -> Whe.
// Bsw[l][(((p*8+kb)*4+quad)*256+f)*8+j] = B_l[p][kb*32+quad*8+j][f]
__global__ __launch_bounds__(256) void bswz_kernel(const float* __restrict__ W,
                                                   const float* __restrict__ Wself,
                                                   const float* __restrict__ Whe,
                                                   unsigned short* __restrict__ Bsw) {
    int gid = blockIdx.x * 256 + threadIdx.x;
    int f = gid & 255;
    int t = gid >> 8;
    int quad = t & 3; t >>= 2;
    int kb = t & 7; t >>= 3;
    int p = t % 10, l = t / 10;
    const float* base = (p == 0) ? Wself + (size_t)l * DD * DD
                      : (p <= 8) ? W + ((size_t)l * 8 + (p - 1)) * DD * DD
                                 : Whe + (size_t)l * DD * DD;
    int k0 = kb * 32 + quad * 8;
    unsigned pk[4];
#pragma unroll
    for (int jj = 0; jj < 4; ++jj)
        pk[jj] = pack2(base[(size_t)(k0 + 2 * jj) * DD + f],
                       base[(size_t)(k0 + 2 * jj + 1) * DD + f]);
    uint4 v = make_uint4(pk[0], pk[1], pk[2], pk[3]);
    *(uint4*)&Bsw[(size_t)gid * 8] = v;
}

__global__ __launch_bounds__(256) void init_x_kernel(float* __restrict__ x,
                                                     unsigned short* __restrict__ xbf) {
    int i = blockIdx.x * 256 + threadIdx.x;
    ((float4*)x)[i] = make_float4(1.f, 1.f, 1.f, 1.f);
    ((uint2*)xbf)[i] = make_uint2(0x3f803f80u, 0x3f803f80u);
}

// ---------------- k1: per-layer relation aggregation (latency regime) ----------------
// One WAVE per node. No barriers, no LDS, ~60 VGPR -> high occupancy; the random
// x-row gather is hidden by wave-level TLP instead of intra-block pipelining
// (rounds 0-3 showed the barrier-coupled fused gather is structurally latency-bound).
// Output: Abf[n][r*256 + k] = (sum_{edges(r,n)} x[src][k]) * invdeg(n), bf16.
// Relation loop is static-unrolled (rule #20: no runtime-indexed register arrays).
__global__ __launch_bounds__(512) void agg_kernel(
    const int* __restrict__ seg_start, const int* __restrict__ esrc,
    const unsigned short* __restrict__ xbf, unsigned short* __restrict__ Abf) {
    int wv = threadIdx.x >> 6, lane = threadIdx.x & 63;
    int n = blockIdx.x * 8 + wv;
    if (n >= NN) return;
    int jb[9];
#pragma unroll
    for (int r = 0; r < 9; ++r) jb[r] = seg_start[n * 8 + r];   // wave-uniform
    float idg = 1.0f / (float)max(jb[8] - jb[0], 1);
    int cofs = lane * 4;                                        // ushort idx, 8B/lane
#pragma unroll
    for (int rr = 0; rr < 8; ++rr) {
        int j0 = jb[rr], j1 = jb[rr + 1];
        float a0 = 0.f, a1 = 0.f, a2 = 0.f, a3 = 0.f;
#pragma unroll 1
        for (int j = j0; j < j1; j += 8) {                      // avg deg/rel = 2
            int rem = j1 - j;
            uint2 gvv[8];
#pragma unroll
            for (int t = 0; t < 8; ++t) {
                int jj = (t < rem) ? j + t : j;                 // clamp: safe addr
                gvv[t] = *(const uint2*)&xbf[(size_t)esrc[jj] * DD + cofs];
            }
#pragma unroll
            for (int t = 0; t < 8; ++t) {
                unsigned vx = (t < rem) ? gvv[t].x : 0u;
                unsigned vy = (t < rem) ? gvv[t].y : 0u;
                a0 += lo2f(vx); a1 += hi2f(vx);
                a2 += lo2f(vy); a3 += hi2f(vy);
            }
        }
        *(uint2*)&Abf[(size_t)n * 2048 + rr * 256 + cofs] =
            make_uint2(pack2(a0 * idg, a1 * idg), pack2(a2 * idg, a3 * idg));
    }
}

// ---------------- k2: per-layer GEMM + LN (compute regime) ----------------
// C[n,f] = sum_k A[n,k] B[k,f]; M=20080 (80x251), K=2560, N=256.
// A K-blocks: q=0 -> xbf, q=1..8 -> Abf[:, (q-1)*256...], q=9 -> eaggbf
// (matches Bsw phase order). A staged per-phase with global_load_lds(16B):
// LDS dest linear, per-lane global source carries the XOR swizzle
// (chunk sc stores A col-chunk sc^(row&31)), so the proven afr/B fragment
// pairing from the fused kernel is reused byte-identically.
// Grid = 251 blocks -> one block per CU, single round, no tail.
// Plain __syncthreads() per phase = proven m97 drain structure.
__global__ __launch_bounds__(512) void gemm_layer_kernel(
    const unsigned short* __restrict__ xbfin, const unsigned short* __restrict__ Abf,
    const unsigned short* __restrict__ eaggbf, const unsigned short* __restrict__ Bswl,
    const float* __restrict__ xin, const float* __restrict__ gl,
    const float* __restrict__ bl, float* __restrict__ xout,
    unsigned short* __restrict__ xbfout) {
    __shared__ __align__(16) unsigned char smem[81920];   // 2 x 40KB A-tiles / Hs overlay
    int tid = threadIdx.x;
    int wv = tid >> 6, lane = tid & 63;
    int row0 = blockIdx.x * BMR;
    int m = lane & 15, quad = lane >> 4;
    f4 acc[5][2] = {};

    // ---- prologue: stage q=0 (xbf rows) into buf0; prefetch B frags gn=0,1 ----
#pragma unroll
    for (int i = 0; i < 5; ++i) {
        int bc = i * 512 + wv * 64;                 // wave-uniform base chunk
        int c = bc + lane;
        int row = c >> 5, sc = c & 31, scs = sc ^ (row & 31);
        const unsigned short* src = xbfin + (size_t)(row0 + row) * DD + scs * 8;
        GLOAD_LDS16(src, smem + (size_t)bc * 16 + (size_t)lane * 16);
    }
    bf8 breg[2][2];
#pragma unroll
    for (int nt = 0; nt < 2; ++nt) {
        breg[0][nt] = *(const bf8*)&Bswl[((size_t)quad * 256 + wv * 32 + nt * 16 + m) * 8];
        breg[1][nt] = *(const bf8*)&Bswl[((size_t)(4 + quad) * 256 + wv * 32 + nt * 16 + m) * 8];
    }
    __syncthreads();                                 // drains vmcnt -> buf0 ready

#pragma unroll 1
    for (int p = 0; p < 10; ++p) {
        unsigned char* bufp = smem + (p & 1) * 40960;
        unsigned char* bufn = smem + ((p + 1) & 1) * 40960;
        // ---- stage A tile for phase q=p+1 (issued early, covered by MFMA) ----
        if (p < 9) {
            int q = p + 1;
            const unsigned short* sb;
            size_t rs;
            if (q <= 8) { sb = Abf + (size_t)row0 * 2048 + (size_t)(q - 1) * 256; rs = 2048; }
            else        { sb = eaggbf + (size_t)row0 * DD; rs = DD; }
#pragma unroll
            for (int i = 0; i < 5; ++i) {
                int bc = i * 512 + wv * 64;
                int c = bc + lane;
                int row = c >> 5, sc = c & 31, scs = sc ^ (row & 31);
                const unsigned short* src = sb + (size_t)row * rs + scs * 8;
                GLOAD_LDS16(src, bufn + (size_t)bc * 16 + (size_t)lane * 16);
            }
        }
        // ---- 8 MFMA steps on bufp; B register-prefetch 2 steps ahead ----
#pragma unroll
        for (int kb = 0; kb < 8; ++kb) {
            bf8 afr[5];
#pragma unroll
            for (int mt = 0; mt < 5; ++mt) {
                int rowl = mt * 16 + m;
                afr[mt] = *(bf8*)&bufp[rowl * 512 + (((kb * 4 + quad) ^ (rowl & 31)) * 16)];
            }
#pragma unroll
            for (int mt = 0; mt < 5; ++mt)
#pragma unroll
                for (int nt = 0; nt < 2; ++nt)
                    acc[mt][nt] = __builtin_amdgcn_mfma_f32_16x16x32_bf16(
                        afr[mt], breg[kb & 1][nt], acc[mt][nt], 0, 0, 0);
            int gn = p * 8 + kb + 2;
            if (gn < 80) {
#pragma unroll
                for (int nt = 0; nt < 2; ++nt)
                    breg[kb & 1][nt] = *(const bf8*)&Bswl[((size_t)gn * 4 + quad) * 2048
                                                          + ((size_t)(wv * 32 + nt * 16 + m)) * 8];
            }
        }
        __syncthreads();                             // staged bufn ready, bufp reads done
    }

    // ---- epilogue: h tile through LDS (overlay); LN+ReLU+residual ----
    float* Hs = (float*)smem;                        // 80 x 256 floats = 80KB
    float4 g  = *(const float4*)&gl[lane * 4];
    float4 bb = *(const float4*)&bl[lane * 4];
#pragma unroll
    for (int mt = 0; mt < 5; ++mt)
#pragma unroll
        for (int nt = 0; nt < 2; ++nt)
#pragma unroll
            for (int rg = 0; rg < 4; ++rg)
                Hs[(mt * 16 + quad * 4 + rg) * 256 + wv * 32 + nt * 16 + m] = acc[mt][nt][rg];
    __syncthreads();
#pragma unroll 1
    for (int rr = 0; rr < 10; ++rr) {
        int row = wv * 10 + rr;
        float4 v = *(float4*)&Hs[row * 256 + lane * 4];
        float s = v.x + v.y + v.z + v.w;
        float q = v.x * v.x + v.y * v.y + v.z * v.z + v.w * v.w;
#pragma unroll
        for (int off = 32; off; off >>= 1) {
            s += __shfl_xor(s, off);
            q += __shfl_xor(q, off);
        }
        float mu  = s * (1.0f / DD);
        float var = q * (1.0f / DD) - mu * mu;
        float rs  = rsqrtf(var + 1e-5f);
        size_t xi = (size_t)(row0 + row) * DD + lane * 4;
        float4 xv = *(const float4*)&xin[xi];
        float4 o;
        o.x = fmaxf((v.x - mu) * rs * g.x + bb.x, 0.0f) + xv.x;
        o.y = fmaxf((v.y - mu) * rs * g.y + bb.y, 0.0f) + xv.y;
        o.z = fmaxf((v.z - mu) * rs * g.z + bb.z, 0.0f) + xv.z;
        o.w = fmaxf((v.w - mu) * rs * g.w + bb.w, 0.0f) + xv.w;
        *(float4*)&xout[xi] = o;
        *(uint2*)&xbfout[xi] = make_uint2(pack2(o.x, o.y), pack2(o.z, o.w));
    }
}

__global__ __launch_bounds__(256) void score_kernel(
    const int* __restrict__ batch, const float* __restrict__ x,
    const float* __restrict__ rel_emb, float* __restrict__ out) {
    int tid = threadIdx.x;
    int wave = tid >> 6, lane = tid & 63;
    int idx = blockIdx.x * 4 + wave;
    int s = batch[idx * 3 + 0], t = batch[idx * 3 + 1], r = batch[idx * 3 + 2];
    float4 sv = *(const float4*)&x[(size_t)s * DD + lane * 4];
    float4 tv = *(const float4*)&x[(size_t)t * DD + lane * 4];
    float4 rv = *(const float4*)&rel_emb[(size_t)r * DD + lane * 4];
    float sum = sv.x * rv.x * tv.x + sv.y * rv.y * tv.y +
                sv.z * rv.z * tv.z + sv.w * rv.w * tv.w;
#pragma unroll
    for (int off = 32; off; off >>= 1) sum += __shfl_xor(sum, off);
    if (lane == 0) out[idx] = sum;
}

extern "C" void kernel_launch(void* const* d_in, const int* in_sizes, int n_in,
                              void* d_out, int out_size, void* d_ws, size_t ws_size,
                              hipStream_t stream) {
    const int*   edge_index = (const int*)d_in[0];
    const int*   srcv   = edge_index;
    const int*   dstv   = edge_index + NE;
    const int*   typev  = (const int*)d_in[1];
    const float* ee     = (const float*)d_in[2];
    const int*   batch  = (const int*)d_in[3];
    const float* W      = (const float*)d_in[4];
    const float* Wself  = (const float*)d_in[5];
    const float* We     = (const float*)d_in[6];
    const float* gamma  = (const float*)d_in[7];
    const float* beta   = (const float*)d_in[8];
    const float* rel_emb= (const float*)d_in[9];
    float* out = (float*)d_out;

    // workspace layout (~169 MB total incl. 82 MB Abf panel)
    float* xA     = (float*)d_ws;                          // NP*256 f32
    float* xB     = xA + (size_t)NP * DD;                  // NP*256 f32
    float* Whe    = xB + (size_t)NP * DD;                  // L*256*256 f32
    float* invdeg = Whe + (size_t)LL * DD * DD;            // NN f32
    unsigned short* xbfA   = (unsigned short*)(invdeg + NN);          // NP*256
    unsigned short* xbfB   = xbfA + (size_t)NP * DD;                  // NP*256
    unsigned short* eaggbf = xbfB + (size_t)NP * DD;                  // NP*256
    unsigned short* Bsw    = eaggbf + (size_t)NP * DD;                // L*2560*256
    int* hist      = (int*)(Bsw + (size_t)LL * 2560 * DD);            // M
    int* excl      = hist + MM;
    int* seg_start = excl + MM;                                       // M+1
    int* cursor    = seg_start + MM + 1;
    int* bsums     = cursor + MM;                                     // 256
    int* esrc      = bsums + 256;                                     // E
    int* eid       = esrc + NE;                                       // E
    unsigned short* Abf =
        (unsigned short*)(((uintptr_t)(eid + NE) + 255) & ~(uintptr_t)255); // NP*2048

    // ---- CSR build ----
    hipMemsetAsync(hist, 0, MM * sizeof(int), stream);
    hist_kernel<<<(NE + 255) / 256, 256, 0, stream>>>(dstv, typev, hist);
    scan1_kernel<<<NSB, 256, 0, stream>>>(hist, excl, bsums);
    scan2_kernel<<<1, 128, 0, stream>>>(bsums);
    add_off_kernel<<<(MM + 255) / 256, 256, 0, stream>>>(excl, bsums, seg_start, cursor);
    invdeg_kernel<<<(NN + 255) / 256, 256, 0, stream>>>(seg_start, invdeg);
    sort_scatter_kernel<<<(NE + 255) / 256, 256, 0, stream>>>(srcv, dstv, typev, cursor, esrc, eid);

    // ---- precomputes ----
    eagg_kernel<<<MM / 8, 256, 0, stream>>>(seg_start, eid, ee, invdeg, eaggbf);
    hipMemsetAsync(Whe, 0, (size_t)LL * DD * DD * sizeof(float), stream);
    whe_kernel<<<LL * 64, 256, 0, stream>>>(We, W, Whe);
    bswz_kernel<<<LL * 10 * 8 * 4, 256, 0, stream>>>(W, Wself, Whe, Bsw);
    init_x_kernel<<<(NP * DD / 4) / 256, 256, 0, stream>>>(xA, xbfA);

    // ---- layers: agg (gather) then GEMM+LN, x double-buffered ----
    float* xin = xA;  float* xout = xB;
    unsigned short* xbin = xbfA;  unsigned short* xbout = xbfB;
    for (int l = 0; l < LL; ++l) {
        agg_kernel<<<NP / 8, 512, 0, stream>>>(seg_start, esrc, xbin, Abf);
        gemm_layer_kernel<<<NGB, 512, 0, stream>>>(xbin, Abf, eaggbf,
            Bsw + (size_t)l * 2560 * DD, xin,
            gamma + (size_t)l * DD, beta + (size_t)l * DD, xout, xbout);
        float* t = xin; xin = xout; xout = t;
        unsigned short* tb = xbin; xbin = xbout; xbout = tb;
    }
    score_kernel<<<(BB * KK) / 4, 256, 0, stream>>>(batch, xin, rel_emb, out);
}

// Round 5
// 755.559 us; speedup vs baseline: 1.3346x; 1.0968x over previous
//
#include <hip/hip_runtime.h>
#include <hip/hip_bf16.h>

#define NN 20000
#define NP 20080            // padded to 80*251 (GEMM row tiles)
#define NE 320000
#define RR 8
#define DD 256
#define LL 6
#define EED 32
#define BB 64
#define KK 32
#define MM (NN * RR)        // 160000 segments, key = dst*8 + rel
#define NSB 79              // scan blocks: ceil(160000 / 2048)
#define BMR 80              // GEMM row-tile
#define NGB 251             // GEMM grid = NP / BMR (<= 256 CUs -> single round)
#define YROW 2304           // Y row: 9 tiles of 256 (r=0..7 relations, 8=self)
#define YROWB 4608          // Y row bytes

typedef __bf16 bf8 __attribute__((ext_vector_type(8)));
typedef float f4 __attribute__((ext_vector_type(4)));

__device__ inline float lo2f(unsigned v) { return __uint_as_float(v << 16); }
__device__ inline float hi2f(unsigned v) { return __uint_as_float(v & 0xffff0000u); }
__device__ inline unsigned short f2bf(float f) {
    unsigned u = __float_as_uint(f);
    return (unsigned short)((u + 0x7fff + ((u >> 16) & 1)) >> 16);
}
__device__ inline unsigned pack2(float lo, float hi) {
    return (unsigned)f2bf(lo) | ((unsigned)f2bf(hi) << 16);
}

// global->LDS direct copy, 16B per lane. LDS dest linear (wave base + lane*16);
// swizzle lives in the per-lane GLOBAL source address (m173 pattern).
#define GLOAD_LDS16(src, dst)                                                  \
    __builtin_amdgcn_global_load_lds(                                          \
        (const __attribute__((address_space(1))) unsigned int*)(src),          \
        (__attribute__((address_space(3))) unsigned int*)(dst), 16, 0, 0)

// ---------------- CSR build (once per call) ----------------

__global__ __launch_bounds__(256) void hist_kernel(const int* __restrict__ dstv,
                                                   const int* __restrict__ typev,
                                                   int* __restrict__ hist) {
    int e = blockIdx.x * 256 + threadIdx.x;
    if (e < NE) atomicAdd(&hist[dstv[e] * 8 + typev[e]], 1);
}

__global__ __launch_bounds__(256) void scan1_kernel(const int* __restrict__ hist,
                                                    int* __restrict__ excl,
                                                    int* __restrict__ bsums) {
    __shared__ int tmp[256];
    int tid = threadIdx.x;
    int base = blockIdx.x * 2048 + tid * 8;
    int v[8]; int s = 0;
#pragma unroll
    for (int i = 0; i < 8; ++i) {
        v[i] = (base + i < MM) ? hist[base + i] : 0;
        s += v[i];
    }
    tmp[tid] = s;
    __syncthreads();
    for (int off = 1; off < 256; off <<= 1) {
        int t = (tid >= off) ? tmp[tid - off] : 0;
        __syncthreads();
        tmp[tid] += t;
        __syncthreads();
    }
    int run = tmp[tid] - s;
#pragma unroll
    for (int i = 0; i < 8; ++i) {
        if (base + i < MM) excl[base + i] = run;
        run += v[i];
    }
    if (tid == 255) bsums[blockIdx.x] = tmp[255];
}

__global__ __launch_bounds__(128) void scan2_kernel(int* __restrict__ bsums) {
    __shared__ int tmp[128];
    int tid = threadIdx.x;
    int orig = (tid < NSB) ? bsums[tid] : 0;
    tmp[tid] = orig;
    __syncthreads();
    for (int off = 1; off < 128; off <<= 1) {
        int t = (tid >= off) ? tmp[tid - off] : 0;
        __syncthreads();
        tmp[tid] += t;
        __syncthreads();
    }
    if (tid < NSB) bsums[tid] = tmp[tid] - orig;
}

__global__ __launch_bounds__(256) void add_off_kernel(const int* __restrict__ excl,
                                                      const int* __restrict__ bsums,
                                                      int* __restrict__ seg_start,
                                                      int* __restrict__ cursor) {
    int i = blockIdx.x * 256 + threadIdx.x;
    if (i < MM) {
        int v = excl[i] + bsums[i >> 11];
        seg_start[i] = v;
        cursor[i] = v;
    }
    if (i == 0) seg_start[MM] = NE;
}

// scatter: pre-bake the Y gather byte-offset (src row + relation block) so the
// per-layer gather needs ZERO relation logic.
__global__ __launch_bounds__(256) void sort_scatter_kernel(
    const int* __restrict__ srcv, const int* __restrict__ dstv,
    const int* __restrict__ typev, int* __restrict__ cursor,
    int* __restrict__ esrcY, int* __restrict__ eid) {
    int e = blockIdx.x * 256 + threadIdx.x;
    if (e < NE) {
        int key = dstv[e] * 8 + typev[e];
        int pos = atomicAdd(&cursor[key], 1);
        esrcY[pos] = srcv[e] * YROWB + typev[e] * 512;
        eid[pos]   = e;
    }
}

__global__ __launch_bounds__(256) void invdeg_kernel(const int* __restrict__ seg_start,
                                                     float* __restrict__ invdeg) {
    int i = blockIdx.x * 256 + threadIdx.x;
    if (i < NN) {
        int d = seg_start[i * 8 + 8] - seg_start[i * 8];
        invdeg[i] = 1.0f / (float)max(d, 1);
    }
}

// ---------------- once-per-call precomputes ----------------

__global__ __launch_bounds__(256) void eagg_kernel(
    const int* __restrict__ seg_start, const int* __restrict__ eid,
    const float* __restrict__ ee, const float* __restrict__ invdeg,
    unsigned short* __restrict__ eaggbf) {
    int tid = threadIdx.x;
    int s = blockIdx.x * 8 + (tid >> 5);
    int j = tid & 31;
    int n = s >> 3, r = s & 7;
    int j0 = seg_start[s], j1 = seg_start[s + 1];
    float sum = 0.0f;
    for (int p = j0; p < j1; ++p)
        sum += ee[eid[p] * EED + j];
    eaggbf[(size_t)n * DD + r * EED + j] = f2bf(sum * invdeg[n]);
}

// Whe split-K over 8 d-chunks of 32, fp32 atomics (Whe pre-zeroed)
__global__ __launch_bounds__(256) void whe_kernel(const float* __restrict__ We,
                                                  const float* __restrict__ W,
                                                  float* __restrict__ Whe) {
    __shared__ float WeS[EED * 32];
    int b = blockIdx.x;
    int l = b >> 6;
    int r = (b >> 3) & 7;
    int dc = b & 7;
    int tid = threadIdx.x;
    {
        int j = tid >> 3, dl = (tid & 7) * 4;
        *(float4*)&WeS[j * 32 + dl] =
            *(const float4*)&We[(size_t)l * EED * DD + (size_t)j * DD + dc * 32 + dl];
    }
    __syncthreads();
    const float* Wr = W + ((size_t)l * 8 + r) * DD * DD + (size_t)dc * 32 * DD;
    float acc[EED];
#pragma unroll
    for (int j = 0; j < EED; ++j) acc[j] = 0.0f;
    for (int dl = 0; dl < 32; ++dl) {
        float w = Wr[(size_t)dl * DD + tid];
#pragma unroll
        for (int j = 0; j < EED; ++j) acc[j] += WeS[j * 32 + dl] * w;
    }
    float* outp = Whe + (size_t)l * DD * DD + r * EED * DD + tid;
#pragma unroll
    for (int j = 0; j < EED; ++j) unsafeAtomicAdd(&outp[j * DD], acc[j]);
}

// B pre-swizzle into MFMA fragment order (bf16).
// Tile order rt: 0..7 -> W[r=rt], 8 -> Wself, 9 -> Whe.
// Bsw[l][(((rt*8+kb)*4+quad)*256+f)*8+j] = B_l[rt][kb*32+quad*8+j][f]
__global__ __launch_bounds__(256) void bswz_kernel(const float* __restrict__ W,
                                                   const float* __restrict__ Wself,
                                                   const float* __restrict__ Whe,
                                                   unsigned short* __restrict__ Bsw) {
    int gid = blockIdx.x * 256 + threadIdx.x;
    int f = gid & 255;
    int t = gid >> 8;
    int quad = t & 3; t >>= 2;
    int kb = t & 7; t >>= 3;
    int p = t % 10, l = t / 10;
    const float* base = (p <= 7) ? W + ((size_t)l * 8 + p) * DD * DD
                      : (p == 8) ? Wself + (size_t)l * DD * DD
                                 : Whe + (size_t)l * DD * DD;
    int k0 = kb * 32 + quad * 8;
    unsigned pk[4];
#pragma unroll
    for (int jj = 0; jj < 4; ++jj)
        pk[jj] = pack2(base[(size_t)(k0 + 2 * jj) * DD + f],
                       base[(size_t)(k0 + 2 * jj + 1) * DD + f]);
    uint4 v = make_uint4(pk[0], pk[1], pk[2], pk[3]);
    *(uint4*)&Bsw[(size_t)gid * 8] = v;
}

__global__ __launch_bounds__(256) void init_x_kernel(float* __restrict__ xA,
                                                     float* __restrict__ xB,
                                                     unsigned short* __restrict__ xbfA,
                                                     unsigned short* __restrict__ xbfB) {
    int i = blockIdx.x * 256 + threadIdx.x;
    ((float4*)xA)[i] = make_float4(1.f, 1.f, 1.f, 1.f);
    ((float4*)xB)[i] = make_float4(1.f, 1.f, 1.f, 1.f);   // pad rows stay valid all layers
    ((uint2*)xbfA)[i] = make_uint2(0x3f803f80u, 0x3f803f80u);
    ((uint2*)xbfB)[i] = make_uint2(0x3f803f80u, 0x3f803f80u);
}

// ---------------- k1: dense GEMM  Out[:, tile rt] = A @ B_rt  ----------------
// transform-then-aggregate: Y[n][rt*256+f] = sum_k x[n][k] * Wcat[rt][k][f].
// A (80 rows x 256 K) staged ONCE in LDS (reuses round-4 verified staging +
// afr fragment code); B streams from L2-resident Bsw with distance-2 register
// prefetch; per-N-tile epilogue goes acc -> Hs(f32 LDS) -> packed bf16 stores.
// Layer call: A=xbf, rt 0..8 (W0..W7, Wself), out=Y stride 2304.
// eterm call: A=eaggbf, rt 9 (Whe), out=etermb stride 256.
__global__ __launch_bounds__(512) void ymm_kernel(
    const unsigned short* __restrict__ Asrc, const unsigned short* __restrict__ Bswl,
    unsigned short* __restrict__ Yout, int rtBeg, int rtEnd, int ostride) {
    __shared__ __align__(16) unsigned char smem[40960 + 81920];  // A tile + Hs f32
    unsigned char* As = smem;
    float* Hs = (float*)(smem + 40960);
    int tid = threadIdx.x;
    int wv = tid >> 6, lane = tid & 63;
    int row0 = blockIdx.x * BMR;
    int m = lane & 15, quad = lane >> 4;

    // ---- stage A once (source-XOR swizzle, linear LDS dest) ----
#pragma unroll
    for (int i = 0; i < 5; ++i) {
        int bc = i * 512 + wv * 64;
        int c = bc + lane;
        int row = c >> 5, sc = c & 31, scs = sc ^ (row & 31);
        GLOAD_LDS16(Asrc + (size_t)(row0 + row) * DD + scs * 8, As + (size_t)c * 16);
    }
    int gn0 = rtBeg * 8, gnEnd = rtEnd * 8;
    bf8 breg[2][2];
#pragma unroll
    for (int nt = 0; nt < 2; ++nt) {
        breg[0][nt] = *(const bf8*)&Bswl[(((size_t)gn0 * 4 + quad) * 256 + wv * 32 + nt * 16 + m) * 8];
        breg[1][nt] = *(const bf8*)&Bswl[(((size_t)(gn0 + 1) * 4 + quad) * 256 + wv * 32 + nt * 16 + m) * 8];
    }
    __syncthreads();                                 // A tile + B frags ready

#pragma unroll 1
    for (int rt = rtBeg; rt < rtEnd; ++rt) {
        f4 acc[5][2] = {};
#pragma unroll
        for (int kb = 0; kb < 8; ++kb) {
            bf8 afr[5];
#pragma unroll
            for (int mt = 0; mt < 5; ++mt) {
                int rowl = mt * 16 + m;
                afr[mt] = *(bf8*)&As[rowl * 512 + (((kb * 4 + quad) ^ (rowl & 31)) * 16)];
            }
#pragma unroll
            for (int mt = 0; mt < 5; ++mt)
#pragma unroll
                for (int nt = 0; nt < 2; ++nt)
                    acc[mt][nt] = __builtin_amdgcn_mfma_f32_16x16x32_bf16(
                        afr[mt], breg[kb & 1][nt], acc[mt][nt], 0, 0, 0);
            int gn = rt * 8 + kb + 2;
            if (gn < gnEnd) {
#pragma unroll
                for (int nt = 0; nt < 2; ++nt)
                    breg[kb & 1][nt] = *(const bf8*)&Bswl[((size_t)gn * 4 + quad) * 2048
                                                          + ((size_t)(wv * 32 + nt * 16 + m)) * 8];
            }
        }
        // ---- per-tile epilogue: acc -> Hs(f32) -> packed bf16 Y stores ----
#pragma unroll
        for (int mt = 0; mt < 5; ++mt)
#pragma unroll
            for (int nt = 0; nt < 2; ++nt)
#pragma unroll
                for (int rg = 0; rg < 4; ++rg)
                    Hs[(mt * 16 + quad * 4 + rg) * 256 + wv * 32 + nt * 16 + m] = acc[mt][nt][rg];
        __syncthreads();
        int colOff = (rt - rtBeg) * 256;
#pragma unroll
        for (int c2 = 0; c2 < 10; ++c2) {
            int li = c2 * 512 + tid;
            int row = li >> 6, u4 = li & 63;
            float4 v = *(float4*)&Hs[row * 256 + u4 * 4];
            *(uint2*)&Yout[(size_t)(row0 + row) * ostride + colOff + u4 * 4] =
                make_uint2(pack2(v.x, v.y), pack2(v.z, v.w));
        }
        __syncthreads();                             // protect Hs for next tile
    }
}

// ---------------- k2: fused gather + LN + residual (latency regime) ----------------
// One wave per node, no LDS, no barriers, tiny VGPR -> deep TLP. Flat loop over
// ALL edges of the node (relation pre-baked into esrcY byte offsets), single
// f32x4 accumulator, then +self block +eterm, LayerNorm, ReLU, +residual.
__global__ __launch_bounds__(512) void aggln_kernel(
    const int* __restrict__ seg_start, const int* __restrict__ esrcY,
    const unsigned short* __restrict__ Y, const unsigned short* __restrict__ eterml,
    const float* __restrict__ xin, const float* __restrict__ gl,
    const float* __restrict__ bl, float* __restrict__ xout,
    unsigned short* __restrict__ xbfout) {
    int tid = threadIdx.x;
    int wv = tid >> 6, lane = tid & 63;
    int n = blockIdx.x * 8 + wv;                    // grid 2500 -> n < 20000 exact
    float4 g  = *(const float4*)&gl[lane * 4];
    float4 bb = *(const float4*)&bl[lane * 4];
    int j0 = seg_start[n * 8], j1 = seg_start[n * 8 + 8];
    float idg = 1.0f / (float)max(j1 - j0, 1);
    const char* Yb = (const char*)Y;
    size_t lo8 = (size_t)(lane * 8);
    float a0 = 0.f, a1 = 0.f, a2 = 0.f, a3 = 0.f;
#pragma unroll 1
    for (int j = j0; j < j1; j += 8) {              // avg deg = 16 -> ~2 batches
        int rem = j1 - j;
        uint2 gvv[8];
#pragma unroll
        for (int t = 0; t < 8; ++t) {
            int jj = (t < rem) ? j + t : j;         // clamp: always-valid addr
            gvv[t] = *(const uint2*)(Yb + (size_t)(unsigned)esrcY[jj] + lo8);
        }
#pragma unroll
        for (int t = 0; t < 8; ++t) {
            unsigned vx = (t < rem) ? gvv[t].x : 0u;
            unsigned vy = (t < rem) ? gvv[t].y : 0u;
            a0 += lo2f(vx); a1 += hi2f(vx);
            a2 += lo2f(vy); a3 += hi2f(vy);
        }
    }
    uint2 sv = *(const uint2*)(Yb + (size_t)n * YROWB + 4096 + lo8);   // self block
    uint2 ev = *(const uint2*)&eterml[(size_t)n * DD + lane * 4];      // edge term
    float h0 = a0 * idg + lo2f(sv.x) + lo2f(ev.x);
    float h1 = a1 * idg + hi2f(sv.x) + hi2f(ev.x);
    float h2 = a2 * idg + lo2f(sv.y) + lo2f(ev.y);
    float h3 = a3 * idg + hi2f(sv.y) + hi2f(ev.y);
    float s = h0 + h1 + h2 + h3;
    float q = h0 * h0 + h1 * h1 + h2 * h2 + h3 * h3;
#pragma unroll
    for (int off = 32; off; off >>= 1) {
        s += __shfl_xor(s, off);
        q += __shfl_xor(q, off);
    }
    float mu  = s * (1.0f / DD);
    float var = q * (1.0f / DD) - mu * mu;
    float rs  = rsqrtf(var + 1e-5f);
    size_t xi = (size_t)n * DD + lane * 4;
    float4 xv = *(const float4*)&xin[xi];
    float4 o;
    o.x = fmaxf((h0 - mu) * rs * g.x + bb.x, 0.0f) + xv.x;
    o.y = fmaxf((h1 - mu) * rs * g.y + bb.y, 0.0f) + xv.y;
    o.z = fmaxf((h2 - mu) * rs * g.z + bb.z, 0.0f) + xv.z;
    o.w = fmaxf((h3 - mu) * rs * g.w + bb.w, 0.0f) + xv.w;
    *(float4*)&xout[xi] = o;
    *(uint2*)&xbfout[xi] = make_uint2(pack2(o.x, o.y), pack2(o.z, o.w));
}

__global__ __launch_bounds__(256) void score_kernel(
    const int* __restrict__ batch, const float* __restrict__ x,
    const float* __restrict__ rel_emb, float* __restrict__ out) {
    int tid = threadIdx.x;
    int wave = tid >> 6, lane = tid & 63;
    int idx = blockIdx.x * 4 + wave;
    int s = batch[idx * 3 + 0], t = batch[idx * 3 + 1], r = batch[idx * 3 + 2];
    float4 sv = *(const float4*)&x[(size_t)s * DD + lane * 4];
    float4 tv = *(const float4*)&x[(size_t)t * DD + lane * 4];
    float4 rv = *(const float4*)&rel_emb[(size_t)r * DD + lane * 4];
    float sum = sv.x * rv.x * tv.x + sv.y * rv.y * tv.y +
                sv.z * rv.z * tv.z + sv.w * rv.w * tv.w;
#pragma unroll
    for (int off = 32; off; off >>= 1) sum += __shfl_xor(sum, off);
    if (lane == 0) out[idx] = sum;
}

extern "C" void kernel_launch(void* const* d_in, const int* in_sizes, int n_in,
                              void* d_out, int out_size, void* d_ws, size_t ws_size,
                              hipStream_t stream) {
    const int*   edge_index = (const int*)d_in[0];
    const int*   srcv   = edge_index;
    const int*   dstv   = edge_index + NE;
    const int*   typev  = (const int*)d_in[1];
    const float* ee     = (const float*)d_in[2];
    const int*   batch  = (const int*)d_in[3];
    const float* W      = (const float*)d_in[4];
    const float* Wself  = (const float*)d_in[5];
    const float* We     = (const float*)d_in[6];
    const float* gamma  = (const float*)d_in[7];
    const float* beta   = (const float*)d_in[8];
    const float* rel_emb= (const float*)d_in[9];
    float* out = (float*)d_out;

    // workspace layout (~198 MB)
    float* xA     = (float*)d_ws;                          // NP*256 f32
    float* xB     = xA + (size_t)NP * DD;                  // NP*256 f32
    float* Whe    = xB + (size_t)NP * DD;                  // L*256*256 f32
    float* invdeg = Whe + (size_t)LL * DD * DD;            // NN f32
    unsigned short* xbfA   = (unsigned short*)(invdeg + NN);          // NP*256
    unsigned short* xbfB   = xbfA + (size_t)NP * DD;                  // NP*256
    unsigned short* eaggbf = xbfB + (size_t)NP * DD;                  // NP*256
    unsigned short* Bsw    = eaggbf + (size_t)NP * DD;                // L*2560*256
    int* hist      = (int*)(Bsw + (size_t)LL * 2560 * DD);            // M
    int* excl      = hist + MM;
    int* seg_start = excl + MM;                                       // M+1
    int* cursor    = seg_start + MM + 1;
    int* bsums     = cursor + MM;                                     // 256
    int* esrcY     = bsums + 256;                                     // E (byte offs)
    int* eid       = esrcY + NE;                                      // E
    unsigned short* etermb =
        (unsigned short*)(((uintptr_t)(eid + NE) + 255) & ~(uintptr_t)255); // NP*256
    unsigned short* Y = etermb + (size_t)NP * DD;                     // NP*2304

    // ---- CSR build ----
    hipMemsetAsync(hist, 0, MM * sizeof(int), stream);
    hist_kernel<<<(NE + 255) / 256, 256, 0, stream>>>(dstv, typev, hist);
    scan1_kernel<<<NSB, 256, 0, stream>>>(hist, excl, bsums);
    scan2_kernel<<<1, 128, 0, stream>>>(bsums);
    add_off_kernel<<<(MM + 255) / 256, 256, 0, stream>>>(excl, bsums, seg_start, cursor);
    invdeg_kernel<<<(NN + 255) / 256, 256, 0, stream>>>(seg_start, invdeg);
    sort_scatter_kernel<<<(NE + 255) / 256, 256, 0, stream>>>(srcv, dstv, typev, cursor, esrcY, eid);

    // ---- precomputes ----
    eagg_kernel<<<MM / 8, 256, 0, stream>>>(seg_start, eid, ee, invdeg, eaggbf);
    hipMemsetAsync(Whe, 0, (size_t)LL * DD * DD * sizeof(float), stream);
    whe_kernel<<<LL * 64, 256, 0, stream>>>(We, W, Whe);
    bswz_kernel<<<LL * 10 * 8 * 4, 256, 0, stream>>>(W, Wself, Whe, Bsw);
    init_x_kernel<<<(NP * DD / 4) / 256, 256, 0, stream>>>(xA, xB, xbfA, xbfB);

    // ---- layers: Y GEMM + eterm GEMM + fused gather/LN, x double-buffered ----
    float* xin = xA;  float* xout = xB;
    unsigned short* xbin = xbfA;  unsigned short* xbout = xbfB;
    for (int l = 0; l < LL; ++l) {
        const unsigned short* Bl = Bsw + (size_t)l * 2560 * DD;
        ymm_kernel<<<NGB, 512, 0, stream>>>(xbin, Bl, Y, 0, 9, YROW);        // x @ [W|Wself]
        ymm_kernel<<<NGB, 512, 0, stream>>>(eaggbf, Bl, etermb, 9, 10, DD);  // eagg @ Whe
        aggln_kernel<<<NN / 8, 512, 0, stream>>>(seg_start, esrcY, Y, etermb,
            xin, gamma + (size_t)l * DD, beta + (size_t)l * DD, xout, xbout);
        float* t = xin; xin = xout; xout = t;
        unsigned short* tb = xbin; xbin = xbout; xbout = tb;
    }
    score_kernel<<<(BB * KK) / 4, 256, 0, stream>>>(batch, xin, rel_emb, out);
}